// Round 17
// baseline (138.836 us; speedup 1.0000x reference)
//
#include <hip/hip_runtime.h>

typedef __attribute__((ext_vector_type(8))) short short8_t;
typedef __attribute__((ext_vector_type(4))) float f32x4;

// ---------------- problem constants ----------------
#define N_ROWS   131072     // 32*64*64
#define DIM      64
#define NE       512
#define DECAYF   0.99f
#define OMDECAY  0.01f
#define EPSF     1e-5f
#define GAP_THR  0.02f      // round-5/11/13 proven threshold

// ---------------- d_out offsets (floats) ----------------
#define Q_OFF    0            // 8388608
#define DIFF_OFF 8388608      // 1
#define IND_OFF  8388609      // 131072
#define CS_OFF   8519681      // 512
#define AVG_OFF  8520193      // 32768
#define EMB_OFF  8552961      // 32768

// ---------------- ws offsets (floats) ----------------
#define WS_ET      0            // 32768 : ET fp32 [code][dim]
#define WS_ENORM   32768        // 512   : ||E_j||^2 fp32
#define WS_EN64    33280        // 1024  : ||E_j||^2 fp64 (512 doubles)
#define WS_CSDIV   34304        // 512   : cs divisor
#define WS_DIFF    34816        // 1
#define WS_RCNT    34817        // 1 (int)
#define WS_IDX     34818        // 131072 (int)
#define WS_RLIST   165890       // 131072 (int)
#define WS_BH      296964       // 16384 floats = 32768 ushort: bf16 hi B-fragments
#define WS_BL      313348       // 16384 floats = 32768 ushort: bf16 lo B-fragments
#define WS_HIST    329732       // 512 (int)
#define WS_BINBASE 330244       // 512 (int)
#define WS_CURSOR  330756       // 512 (int)
#define WS_SORTED  331268       // 131072 (int)
#define WS_ACCUM   462340       // 32768 : embed_sum accumulator [code][dim]

__device__ __forceinline__ ushort f32_to_bf16_rn(float f) {
    unsigned u = __float_as_uint(f);
    unsigned r = (u + 0x7FFFu + ((u >> 16) & 1u)) >> 16;
    return (ushort)r;
}
__device__ __forceinline__ float bf16_to_f32(ushort h) {
    return __uint_as_float(((unsigned)h) << 16);
}

// ============================================================
// prep: merged prep1+prep2. Block per code (512 x 64).
// ============================================================
__global__ __launch_bounds__(64) void prep_kernel(const float* __restrict__ embed,
                                                  float* __restrict__ ws) {
    const int c = blockIdx.x;    // code 0..511
    const int d = threadIdx.x;   // dim 0..63
    float v = embed[d * NE + c];
    ws[WS_ET + c * DIM + d] = v;

    ushort hb = f32_to_bf16_rn(v);
    float  lf = v - bf16_to_f32(hb);
    ushort lb = f32_to_bf16_rn(lf);

    // fragment order: tile T=c>>4, n=c&15, kstep s=d>>5, k8=(d>>3)&3, j=d&7
    const int T  = c >> 4;
    const int n  = c & 15;
    const int s  = d >> 5;
    const int k8 = (d >> 3) & 3;
    const int jj = d & 7;
    const int l  = k8 * 16 + n;
    const int idx = (T * 2 + s) * 512 + l * 8 + jj;
    ((ushort*)(ws + WS_BH))[idx] = hb;
    ((ushort*)(ws + WS_BL))[idx] = lb;

    double sq = (double)v * (double)v;
    #pragma unroll
    for (int off = 32; off > 0; off >>= 1) sq += __shfl_down(sq, off, 64);
    if (d == 0) {
        ws[WS_ENORM + c] = (float)sq;
        ((double*)(ws + WS_EN64))[c] = sq;
        ((int*)ws)[WS_HIST + c] = 0;
        if (c == 0) {
            ws[WS_DIFF] = 0.0f;
            ((int*)ws)[WS_RCNT] = 0;
        }
    }
    ws[WS_ACCUM + c * DIM + d] = 0.0f;
}

// ============================================================
// dist: ROUND-13 VERBATIM body (measured 44.1 us) + fused per-block
// LDS histogram at the existing IDX-write point (pattern proven in
// round 6). Two barriers added; <=128 nonzero-bin flush atomics/block.
// 1024 blocks x 256 threads (4 waves); wave = 32 rows x 512 codes.
// ============================================================
__global__ __launch_bounds__(256) void dist_kernel(const float* __restrict__ input,
                                                   float* __restrict__ ws) {
    __shared__ int bh[NE];

    const int tid  = threadIdx.x;
    const int lane = tid & 63;
    const int wv   = tid >> 6;
    const int r0   = blockIdx.x * 128 + wv * 32;
    const int n15  = lane & 15;
    const int koff = (lane >> 4) * 8;

    for (int e = tid; e < NE; e += 256) bh[e] = 0;
    __syncthreads();

    short8_t Ahi[2][2], Alo[2][2];
    #pragma unroll
    for (int sub = 0; sub < 2; sub++) {
        const float* rp = input + (size_t)(r0 + sub * 16 + n15) * DIM + koff;
        #pragma unroll
        for (int s = 0; s < 2; s++) {
            float4 x0 = *(const float4*)(rp + s * 32);
            float4 x1 = *(const float4*)(rp + s * 32 + 4);
            float xf[8] = {x0.x, x0.y, x0.z, x0.w, x1.x, x1.y, x1.z, x1.w};
            short8_t h, l;
            #pragma unroll
            for (int e = 0; e < 8; e++) {
                ushort hb = f32_to_bf16_rn(xf[e]);
                float  lf = xf[e] - bf16_to_f32(hb);
                ushort lb = f32_to_bf16_rn(lf);
                h[e] = (short)hb;
                l[e] = (short)lb;
            }
            Ahi[sub][s] = h;
            Alo[sub][s] = l;
        }
    }

    const ushort* bhp = (const ushort*)(ws + WS_BH) + lane * 8;
    const ushort* blp = (const ushort*)(ws + WS_BL) + lane * 8;

    float m1[8], m2[8];
    int   j1[8];
    #pragma unroll
    for (int i = 0; i < 8; i++) { m1[i] = 3.4e38f; m2[i] = 3.4e38f; j1[i] = 0; }

    #pragma unroll 2
    for (int T = 0; T < 32; T++) {
        short8_t Bh0 = *(const short8_t*)(bhp + T * 1024);
        short8_t Bh1 = *(const short8_t*)(bhp + T * 1024 + 512);
        short8_t Bl0 = *(const short8_t*)(blp + T * 1024);
        short8_t Bl1 = *(const short8_t*)(blp + T * 1024 + 512);

        f32x4 aa = {0.f, 0.f, 0.f, 0.f};
        f32x4 ab = {0.f, 0.f, 0.f, 0.f};
        aa = __builtin_amdgcn_mfma_f32_16x16x32_bf16(Ahi[0][0], Bh0, aa, 0, 0, 0);
        ab = __builtin_amdgcn_mfma_f32_16x16x32_bf16(Ahi[1][0], Bh0, ab, 0, 0, 0);
        aa = __builtin_amdgcn_mfma_f32_16x16x32_bf16(Alo[0][0], Bh0, aa, 0, 0, 0);
        ab = __builtin_amdgcn_mfma_f32_16x16x32_bf16(Alo[1][0], Bh0, ab, 0, 0, 0);
        aa = __builtin_amdgcn_mfma_f32_16x16x32_bf16(Ahi[0][0], Bl0, aa, 0, 0, 0);
        ab = __builtin_amdgcn_mfma_f32_16x16x32_bf16(Ahi[1][0], Bl0, ab, 0, 0, 0);
        aa = __builtin_amdgcn_mfma_f32_16x16x32_bf16(Ahi[0][1], Bh1, aa, 0, 0, 0);
        ab = __builtin_amdgcn_mfma_f32_16x16x32_bf16(Ahi[1][1], Bh1, ab, 0, 0, 0);
        aa = __builtin_amdgcn_mfma_f32_16x16x32_bf16(Alo[0][1], Bh1, aa, 0, 0, 0);
        ab = __builtin_amdgcn_mfma_f32_16x16x32_bf16(Alo[1][1], Bh1, ab, 0, 0, 0);
        aa = __builtin_amdgcn_mfma_f32_16x16x32_bf16(Ahi[0][1], Bl1, aa, 0, 0, 0);
        ab = __builtin_amdgcn_mfma_f32_16x16x32_bf16(Ahi[1][1], Bl1, ab, 0, 0, 0);

        const float en = ws[WS_ENORM + T * 16 + n15];
        const int   jc = T * 16 + n15;
        #pragma unroll
        for (int q = 0; q < 4; q++) {
            float da = fmaf(-2.0f, aa[q], en);
            m2[q]    = fminf(m2[q], fmaxf(m1[q], da));
            j1[q]    = (da < m1[q]) ? jc : j1[q];
            m1[q]    = fminf(m1[q], da);
            float db = fmaf(-2.0f, ab[q], en);
            m2[q+4]  = fminf(m2[q+4], fmaxf(m1[q+4], db));
            j1[q+4]  = (db < m1[q+4]) ? jc : j1[q+4];
            m1[q+4]  = fminf(m1[q+4], db);
        }
    }

    #pragma unroll
    for (int off = 1; off < 16; off <<= 1) {
        #pragma unroll
        for (int i = 0; i < 8; i++) {
            float b1 = __shfl_xor(m1[i], off, 64);
            float b2 = __shfl_xor(m2[i], off, 64);
            int   bj = __shfl_xor(j1[i], off, 64);
            float a1 = m1[i];
            float nm2 = fminf(fminf(m2[i], b2), fmaxf(a1, b1));
            bool takeB = (b1 < a1) || (b1 == a1 && bj < j1[i]);
            m1[i] = takeB ? b1 : a1;
            j1[i] = takeB ? bj : j1[i];
            m2[i] = nm2;
        }
    }

    if (n15 == 0) {
        #pragma unroll
        for (int i = 0; i < 8; i++) {
            int sub = i >> 2, q = i & 3;
            int r = r0 + sub * 16 + (lane >> 4) * 4 + q;
            ((int*)ws)[WS_IDX + r] = j1[i];
            atomicAdd(&bh[j1[i]], 1);
            if (m2[i] - m1[i] < GAP_THR) {
                int pos = atomicAdd((int*)ws + WS_RCNT, 1);
                ((int*)ws)[WS_RLIST + pos] = r;
            }
        }
    }

    __syncthreads();
    for (int e = tid; e < NE; e += 256) {
        int h = bh[e];
        if (h) atomicAdd((int*)ws + WS_HIST + e, h);
    }
}

// ============================================================
// refine: exact fp64 re-resolution of flagged rows; fixes IDX and
// adjusts WS_HIST by +-1 on change (pattern proven in round 6).
// ============================================================
__global__ __launch_bounds__(256) void refine_kernel(const float* __restrict__ input,
                                                     float* __restrict__ ws) {
    __shared__ float rowf[4][DIM];
    const int cnt  = ((const int*)ws)[WS_RCNT];
    const int lane = threadIdx.x & 63;
    const int wv   = threadIdx.x >> 6;
    const double* en64 = (const double*)(ws + WS_EN64);

    for (int ii = blockIdx.x * 4 + wv; ii < cnt; ii += 2048) {
        const int r = ((const int*)ws)[WS_RLIST + ii];
        rowf[wv][lane] = input[(size_t)r * DIM + lane];
        double bd = 1e300;
        int    bj = 0x7fffffff;
        for (int kk = 0; kk < 8; kk++) {
            int j = kk * 64 + lane;
            const float* ep = ws + WS_ET + j * DIM;
            double s0 = 0.0, s1 = 0.0;
            #pragma unroll 8
            for (int d = 0; d < DIM; d += 2) {
                s0 = fma((double)ep[d],     (double)rowf[wv][d],     s0);
                s1 = fma((double)ep[d + 1], (double)rowf[wv][d + 1], s1);
            }
            double dist = en64[j] - 2.0 * (s0 + s1);
            if (dist < bd || (dist == bd && j < bj)) { bd = dist; bj = j; }
        }
        #pragma unroll
        for (int off = 32; off > 0; off >>= 1) {
            double od = __shfl_down(bd, off, 64);
            int    oj = __shfl_down(bj, off, 64);
            if (od < bd || (od == bd && oj < bj)) { bd = od; bj = oj; }
        }
        if (lane == 0) {
            const int jold = ((const int*)ws)[WS_IDX + r];
            if (bj != jold) {
                ((int*)ws)[WS_IDX + r] = bj;
                atomicAdd((int*)ws + WS_HIST + jold, -1);
                atomicAdd((int*)ws + WS_HIST + bj, 1);
            }
        }
    }
}

// ============================================================
// scanfin (1 block x 512): CS EMA, exclusive scan -> binbase/cursor,
// n-reduce, cs divisor.
// ============================================================
__global__ __launch_bounds__(512) void scanfin_kernel(const float* __restrict__ cluster_size,
                                                      float* __restrict__ ws,
                                                      float* __restrict__ out) {
    __shared__ int wsums[8];
    __shared__ float red[8];
    const int t    = threadIdx.x;
    const int lane = t & 63;
    const int wv   = t >> 6;
    const int v    = ((const int*)ws)[WS_HIST + t];
    const float csnew = fmaf(cluster_size[t], DECAYF, OMDECAY * (float)v);
    out[CS_OFF + t] = csnew;

    int x = v;
    #pragma unroll
    for (int off = 1; off < 64; off <<= 1) {
        int y = __shfl_up(x, off, 64);
        if (lane >= off) x += y;
    }
    if (lane == 63) wsums[wv] = x;

    float s = csnew;
    #pragma unroll
    for (int off = 32; off > 0; off >>= 1) s += __shfl_down(s, off, 64);
    if (lane == 0) red[wv] = s;
    __syncthreads();

    int add = 0;
    for (int w = 0; w < wv; w++) add += wsums[w];
    const int excl = x + add - v;
    ((int*)ws)[WS_BINBASE + t] = excl;
    ((int*)ws)[WS_CURSOR + t]  = excl;

    float n = red[0] + red[1] + red[2] + red[3] + red[4] + red[5] + red[6] + red[7];
    ws[WS_CSDIV + t] = (csnew + EPSF) / (n + (float)NE * EPSF) * n;
}

// ============================================================
// place: skew-proof counting-sort placement.
// ============================================================
__global__ __launch_bounds__(256) void place_kernel(float* __restrict__ ws) {
    __shared__ int lhist[NE];
    __shared__ int lbase[NE];
    __shared__ int lcur[NE];
    const int tid  = threadIdx.x;
    const int base = blockIdx.x * 256;

    for (int e = tid; e < NE; e += 256) { lhist[e] = 0; lcur[e] = 0; }
    __syncthreads();

    const int r = base + tid;
    const int j = ((const int*)ws)[WS_IDX + r];
    atomicAdd(&lhist[j], 1);
    __syncthreads();

    for (int e = tid; e < NE; e += 256)
        if (lhist[e]) lbase[e] = atomicAdd((int*)ws + WS_CURSOR + e, lhist[e]);
    __syncthreads();

    const int pos = lbase[j] + atomicAdd(&lcur[j], 1);
    ((int*)ws)[WS_SORTED + pos] = r;
}

// ============================================================
// sum: ROUND-13 VERBATIM. Fused segment-sum + Q write + IND + diff.
// ============================================================
__global__ __launch_bounds__(256) void sum_kernel(const float* __restrict__ input,
                                                  float* __restrict__ ws,
                                                  float* __restrict__ out) {
    __shared__ float wred[4];
    const int lane = threadIdx.x & 63;
    const int wv   = threadIdx.x >> 6;
    const int i0   = (blockIdx.x * 4 + wv) * 32;

    const int rv = ((const int*)ws)[WS_SORTED + i0 + (lane & 31)];
    const int jv = ((const int*)ws)[WS_IDX + rv];

    float acc  = 0.0f;
    float dacc = 0.0f;
    int   jcur = __shfl(jv, 0, 64);

    #pragma unroll
    for (int k = 0; k < 32; k += 8) {
        int   rr[8], jj[8];
        float v[8], q[8];
        #pragma unroll
        for (int u = 0; u < 8; u++) {
            rr[u] = __shfl(rv, k + u, 64);
            jj[u] = __shfl(jv, k + u, 64);
        }
        #pragma unroll
        for (int u = 0; u < 8; u++) v[u] = input[(size_t)rr[u] * DIM + lane];
        #pragma unroll
        for (int u = 0; u < 8; u++) q[u] = ws[WS_ET + jj[u] * DIM + lane];

        #pragma unroll
        for (int u = 0; u < 8; u++) {
            out[Q_OFF + (size_t)rr[u] * DIM + lane] = q[u];
            float dd = q[u] - v[u];
            dacc = fmaf(dd, dd, dacc);
            if (lane == 0) out[IND_OFF + rr[u]] = (float)jj[u];
            if (jj[u] != jcur) {
                atomicAdd(&ws[WS_ACCUM + jcur * DIM + lane], acc);
                acc = 0.0f;
                jcur = jj[u];
            }
            acc += v[u];
        }
    }
    atomicAdd(&ws[WS_ACCUM + jcur * DIM + lane], acc);

    #pragma unroll
    for (int off = 1; off < 64; off <<= 1) dacc += __shfl_xor(dacc, off, 64);
    if (lane == 0) wred[wv] = dacc;
    __syncthreads();
    if (threadIdx.x == 0)
        atomicAdd(&ws[WS_DIFF], wred[0] + wred[1] + wred[2] + wred[3]);
}

// ============================================================
// emaout: fused new_embed_avg + new_embed epilogue + diff finalize.
// ============================================================
__global__ __launch_bounds__(512) void emaout_kernel(const float* __restrict__ embed_avg,
                                                     const float* __restrict__ ws,
                                                     float* __restrict__ out) {
    const int e = blockIdx.x * 512 + threadIdx.x;
    const int d = e >> 9;
    const int j = e & (NE - 1);
    float s   = ws[WS_ACCUM + j * DIM + d];
    float avg = fmaf(embed_avg[e], DECAYF, OMDECAY * s);
    out[AVG_OFF + e] = avg;
    out[EMB_OFF + e] = avg / ws[WS_CSDIV + j];
    if (e == 0) out[DIFF_OFF] = ws[WS_DIFF] * (1.0f / 8388608.0f);
}

// ============================================================
extern "C" void kernel_launch(void* const* d_in, const int* in_sizes, int n_in,
                              void* d_out, int out_size, void* d_ws, size_t ws_size,
                              hipStream_t stream) {
    const float* input        = (const float*)d_in[0];
    const float* embed        = (const float*)d_in[1];
    const float* cluster_size = (const float*)d_in[2];
    const float* embed_avg    = (const float*)d_in[3];
    float* out = (float*)d_out;
    float* ws  = (float*)d_ws;

    prep_kernel<<<512, 64, 0, stream>>>(embed, ws);
    dist_kernel<<<N_ROWS / 128, 256, 0, stream>>>(input, ws);
    refine_kernel<<<512, 256, 0, stream>>>(input, ws);
    scanfin_kernel<<<1, 512, 0, stream>>>(cluster_size, ws, out);
    place_kernel<<<512, 256, 0, stream>>>(ws);
    sum_kernel<<<N_ROWS / 128, 256, 0, stream>>>(input, ws, out);
    emaout_kernel<<<64, 512, 0, stream>>>(embed_avg, ws, out);
}

// Round 18
// 116.036 us; speedup vs baseline: 1.1965x; 1.1965x over previous
//
#include <hip/hip_runtime.h>

typedef __attribute__((ext_vector_type(8))) short short8_t;
typedef __attribute__((ext_vector_type(4))) float f32x4;

// ---------------- problem constants ----------------
#define N_ROWS   131072     // 32*64*64
#define DIM      64
#define NE       512
#define DECAYF   0.99f
#define OMDECAY  0.01f
#define EPSF     1e-5f
#define GAP_THR  0.02f      // round-5/11/13 proven threshold

// ---------------- d_out offsets (floats) ----------------
#define Q_OFF    0            // 8388608
#define DIFF_OFF 8388608      // 1
#define IND_OFF  8388609      // 131072
#define CS_OFF   8519681      // 512
#define AVG_OFF  8520193      // 32768
#define EMB_OFF  8552961      // 32768

// ---------------- ws offsets (floats) ----------------
#define WS_ET      0            // 32768 : ET fp32 [code][dim]
#define WS_ENORM   32768        // 512   : ||E_j||^2 fp32
#define WS_EN64    33280        // 1024  : ||E_j||^2 fp64 (512 doubles)
#define WS_CSDIV   34304        // 512   : cs divisor
#define WS_DIFF    34816        // 1
#define WS_RCNT    34817        // 1 (int)
#define WS_IDX     34818        // 131072 (int)
#define WS_RLIST   165890       // 131072 (int)
#define WS_BH      296964       // 16384 floats = 32768 ushort: bf16 hi B-fragments
#define WS_BL      313348       // 16384 floats = 32768 ushort: bf16 lo B-fragments
#define WS_HIST    329732       // 512 (int)
#define WS_BINBASE 330244       // 512 (int)
#define WS_CURSOR  330756       // 512 (int)
#define WS_SORTED  331268       // 131072 (int)
#define WS_ACCUM   462340       // 32768 : embed_sum accumulator [code][dim]

__device__ __forceinline__ ushort f32_to_bf16_rn(float f) {
    unsigned u = __float_as_uint(f);
    unsigned r = (u + 0x7FFFu + ((u >> 16) & 1u)) >> 16;
    return (ushort)r;
}
__device__ __forceinline__ float bf16_to_f32(ushort h) {
    return __uint_as_float(((unsigned)h) << 16);
}

// ============================================================
// prep: merged prep1+prep2. Block per code (512 x 64).
// ============================================================
__global__ __launch_bounds__(64) void prep_kernel(const float* __restrict__ embed,
                                                  float* __restrict__ ws) {
    const int c = blockIdx.x;    // code 0..511
    const int d = threadIdx.x;   // dim 0..63
    float v = embed[d * NE + c];
    ws[WS_ET + c * DIM + d] = v;

    ushort hb = f32_to_bf16_rn(v);
    float  lf = v - bf16_to_f32(hb);
    ushort lb = f32_to_bf16_rn(lf);

    // fragment order: tile T=c>>4, n=c&15, kstep s=d>>5, k8=(d>>3)&3, j=d&7
    const int T  = c >> 4;
    const int n  = c & 15;
    const int s  = d >> 5;
    const int k8 = (d >> 3) & 3;
    const int jj = d & 7;
    const int l  = k8 * 16 + n;
    const int idx = (T * 2 + s) * 512 + l * 8 + jj;
    ((ushort*)(ws + WS_BH))[idx] = hb;
    ((ushort*)(ws + WS_BL))[idx] = lb;

    double sq = (double)v * (double)v;
    #pragma unroll
    for (int off = 32; off > 0; off >>= 1) sq += __shfl_down(sq, off, 64);
    if (d == 0) {
        ws[WS_ENORM + c] = (float)sq;
        ((double*)(ws + WS_EN64))[c] = sq;
        ((int*)ws)[WS_HIST + c] = 0;
        if (c == 0) {
            ws[WS_DIFF] = 0.0f;
            ((int*)ws)[WS_RCNT] = 0;
        }
    }
    ws[WS_ACCUM + c * DIM + d] = 0.0f;
}

// ============================================================
// dist: ROUND-13 VERBATIM (measured 44.1 us). MFMA bf16 3-term split,
// zero C-init, en in epilogue via fmaf(-2,acc,en), j1-ternary argmin +
// second-min, butterfly reduce, IDX + refine-flag writes. Barrier-free;
// NO LDS (8 structural-modification attempts all regressed — do not touch).
// 1024 blocks x 256 threads (4 waves); wave = 32 rows x 512 codes.
// ============================================================
__global__ __launch_bounds__(256) void dist_kernel(const float* __restrict__ input,
                                                   float* __restrict__ ws) {
    const int tid  = threadIdx.x;
    const int lane = tid & 63;
    const int wv   = tid >> 6;
    const int r0   = blockIdx.x * 128 + wv * 32;
    const int n15  = lane & 15;
    const int koff = (lane >> 4) * 8;

    short8_t Ahi[2][2], Alo[2][2];
    #pragma unroll
    for (int sub = 0; sub < 2; sub++) {
        const float* rp = input + (size_t)(r0 + sub * 16 + n15) * DIM + koff;
        #pragma unroll
        for (int s = 0; s < 2; s++) {
            float4 x0 = *(const float4*)(rp + s * 32);
            float4 x1 = *(const float4*)(rp + s * 32 + 4);
            float xf[8] = {x0.x, x0.y, x0.z, x0.w, x1.x, x1.y, x1.z, x1.w};
            short8_t h, l;
            #pragma unroll
            for (int e = 0; e < 8; e++) {
                ushort hb = f32_to_bf16_rn(xf[e]);
                float  lf = xf[e] - bf16_to_f32(hb);
                ushort lb = f32_to_bf16_rn(lf);
                h[e] = (short)hb;
                l[e] = (short)lb;
            }
            Ahi[sub][s] = h;
            Alo[sub][s] = l;
        }
    }

    const ushort* bhp = (const ushort*)(ws + WS_BH) + lane * 8;
    const ushort* blp = (const ushort*)(ws + WS_BL) + lane * 8;

    float m1[8], m2[8];
    int   j1[8];
    #pragma unroll
    for (int i = 0; i < 8; i++) { m1[i] = 3.4e38f; m2[i] = 3.4e38f; j1[i] = 0; }

    #pragma unroll 2
    for (int T = 0; T < 32; T++) {
        short8_t Bh0 = *(const short8_t*)(bhp + T * 1024);
        short8_t Bh1 = *(const short8_t*)(bhp + T * 1024 + 512);
        short8_t Bl0 = *(const short8_t*)(blp + T * 1024);
        short8_t Bl1 = *(const short8_t*)(blp + T * 1024 + 512);

        f32x4 aa = {0.f, 0.f, 0.f, 0.f};
        f32x4 ab = {0.f, 0.f, 0.f, 0.f};
        aa = __builtin_amdgcn_mfma_f32_16x16x32_bf16(Ahi[0][0], Bh0, aa, 0, 0, 0);
        ab = __builtin_amdgcn_mfma_f32_16x16x32_bf16(Ahi[1][0], Bh0, ab, 0, 0, 0);
        aa = __builtin_amdgcn_mfma_f32_16x16x32_bf16(Alo[0][0], Bh0, aa, 0, 0, 0);
        ab = __builtin_amdgcn_mfma_f32_16x16x32_bf16(Alo[1][0], Bh0, ab, 0, 0, 0);
        aa = __builtin_amdgcn_mfma_f32_16x16x32_bf16(Ahi[0][0], Bl0, aa, 0, 0, 0);
        ab = __builtin_amdgcn_mfma_f32_16x16x32_bf16(Ahi[1][0], Bl0, ab, 0, 0, 0);
        aa = __builtin_amdgcn_mfma_f32_16x16x32_bf16(Ahi[0][1], Bh1, aa, 0, 0, 0);
        ab = __builtin_amdgcn_mfma_f32_16x16x32_bf16(Ahi[1][1], Bh1, ab, 0, 0, 0);
        aa = __builtin_amdgcn_mfma_f32_16x16x32_bf16(Alo[0][1], Bh1, aa, 0, 0, 0);
        ab = __builtin_amdgcn_mfma_f32_16x16x32_bf16(Alo[1][1], Bh1, ab, 0, 0, 0);
        aa = __builtin_amdgcn_mfma_f32_16x16x32_bf16(Ahi[0][1], Bl1, aa, 0, 0, 0);
        ab = __builtin_amdgcn_mfma_f32_16x16x32_bf16(Ahi[1][1], Bl1, ab, 0, 0, 0);

        const float en = ws[WS_ENORM + T * 16 + n15];
        const int   jc = T * 16 + n15;
        #pragma unroll
        for (int q = 0; q < 4; q++) {
            float da = fmaf(-2.0f, aa[q], en);
            m2[q]    = fminf(m2[q], fmaxf(m1[q], da));
            j1[q]    = (da < m1[q]) ? jc : j1[q];
            m1[q]    = fminf(m1[q], da);
            float db = fmaf(-2.0f, ab[q], en);
            m2[q+4]  = fminf(m2[q+4], fmaxf(m1[q+4], db));
            j1[q+4]  = (db < m1[q+4]) ? jc : j1[q+4];
            m1[q+4]  = fminf(m1[q+4], db);
        }
    }

    #pragma unroll
    for (int off = 1; off < 16; off <<= 1) {
        #pragma unroll
        for (int i = 0; i < 8; i++) {
            float b1 = __shfl_xor(m1[i], off, 64);
            float b2 = __shfl_xor(m2[i], off, 64);
            int   bj = __shfl_xor(j1[i], off, 64);
            float a1 = m1[i];
            float nm2 = fminf(fminf(m2[i], b2), fmaxf(a1, b1));
            bool takeB = (b1 < a1) || (b1 == a1 && bj < j1[i]);
            m1[i] = takeB ? b1 : a1;
            j1[i] = takeB ? bj : j1[i];
            m2[i] = nm2;
        }
    }

    if (n15 == 0) {
        #pragma unroll
        for (int i = 0; i < 8; i++) {
            int sub = i >> 2, q = i & 3;
            int r = r0 + sub * 16 + (lane >> 4) * 4 + q;
            ((int*)ws)[WS_IDX + r] = j1[i];
            if (m2[i] - m1[i] < GAP_THR) {
                int pos = atomicAdd((int*)ws + WS_RCNT, 1);
                ((int*)ws)[WS_RLIST + pos] = r;
            }
        }
    }
}

// ============================================================
// refine: exact fp64 re-resolution of flagged rows (fix IDX only).
// 512 blocks x 256 threads; wave per row, 2048-way parallel.
// ============================================================
__global__ __launch_bounds__(256) void refine_kernel(const float* __restrict__ input,
                                                     float* __restrict__ ws) {
    __shared__ float rowf[4][DIM];
    const int cnt  = ((const int*)ws)[WS_RCNT];
    const int lane = threadIdx.x & 63;
    const int wv   = threadIdx.x >> 6;
    const double* en64 = (const double*)(ws + WS_EN64);

    for (int ii = blockIdx.x * 4 + wv; ii < cnt; ii += 2048) {
        const int r = ((const int*)ws)[WS_RLIST + ii];
        rowf[wv][lane] = input[(size_t)r * DIM + lane];
        double bd = 1e300;
        int    bj = 0x7fffffff;
        for (int kk = 0; kk < 8; kk++) {
            int j = kk * 64 + lane;
            const float* ep = ws + WS_ET + j * DIM;
            double s0 = 0.0, s1 = 0.0;
            #pragma unroll 8
            for (int d = 0; d < DIM; d += 2) {
                s0 = fma((double)ep[d],     (double)rowf[wv][d],     s0);
                s1 = fma((double)ep[d + 1], (double)rowf[wv][d + 1], s1);
            }
            double dist = en64[j] - 2.0 * (s0 + s1);
            if (dist < bd || (dist == bd && j < bj)) { bd = dist; bj = j; }
        }
        #pragma unroll
        for (int off = 32; off > 0; off >>= 1) {
            double od = __shfl_down(bd, off, 64);
            int    oj = __shfl_down(bj, off, 64);
            if (od < bd || (od == bd && oj < bj)) { bd = od; bj = oj; }
        }
        if (lane == 0) ((int*)ws)[WS_IDX + r] = bj;
    }
}

// ============================================================
// hist: build WS_HIST from final IDX. 128 blocks x 256 threads.
// ============================================================
__global__ __launch_bounds__(256) void hist_kernel(float* __restrict__ ws) {
    __shared__ int hist[NE];
    const int tid = threadIdx.x;
    for (int e = tid; e < NE; e += 256) hist[e] = 0;
    __syncthreads();

    const int4 j4 = *((const int4*)((const int*)ws + WS_IDX) + blockIdx.x * 256 + tid);
    atomicAdd(&hist[j4.x], 1);
    atomicAdd(&hist[j4.y], 1);
    atomicAdd(&hist[j4.z], 1);
    atomicAdd(&hist[j4.w], 1);
    __syncthreads();

    for (int e = tid; e < NE; e += 256) {
        int h = hist[e];
        if (h) atomicAdd((int*)ws + WS_HIST + e, h);
    }
}

// ============================================================
// scanfin (1 block x 512): CS EMA, exclusive scan -> binbase/cursor,
// n-reduce, cs divisor.
// ============================================================
__global__ __launch_bounds__(512) void scanfin_kernel(const float* __restrict__ cluster_size,
                                                      float* __restrict__ ws,
                                                      float* __restrict__ out) {
    __shared__ int wsums[8];
    __shared__ float red[8];
    const int t    = threadIdx.x;
    const int lane = t & 63;
    const int wv   = t >> 6;
    const int v    = ((const int*)ws)[WS_HIST + t];
    const float csnew = fmaf(cluster_size[t], DECAYF, OMDECAY * (float)v);
    out[CS_OFF + t] = csnew;

    int x = v;
    #pragma unroll
    for (int off = 1; off < 64; off <<= 1) {
        int y = __shfl_up(x, off, 64);
        if (lane >= off) x += y;
    }
    if (lane == 63) wsums[wv] = x;

    float s = csnew;
    #pragma unroll
    for (int off = 32; off > 0; off >>= 1) s += __shfl_down(s, off, 64);
    if (lane == 0) red[wv] = s;
    __syncthreads();

    int add = 0;
    for (int w = 0; w < wv; w++) add += wsums[w];
    const int excl = x + add - v;
    ((int*)ws)[WS_BINBASE + t] = excl;
    ((int*)ws)[WS_CURSOR + t]  = excl;

    float n = red[0] + red[1] + red[2] + red[3] + red[4] + red[5] + red[6] + red[7];
    ws[WS_CSDIV + t] = (csnew + EPSF) / (n + (float)NE * EPSF) * n;
}

// ============================================================
// place: skew-proof counting-sort placement.
// ============================================================
__global__ __launch_bounds__(256) void place_kernel(float* __restrict__ ws) {
    __shared__ int lhist[NE];
    __shared__ int lbase[NE];
    __shared__ int lcur[NE];
    const int tid  = threadIdx.x;
    const int base = blockIdx.x * 256;

    for (int e = tid; e < NE; e += 256) { lhist[e] = 0; lcur[e] = 0; }
    __syncthreads();

    const int r = base + tid;
    const int j = ((const int*)ws)[WS_IDX + r];
    atomicAdd(&lhist[j], 1);
    __syncthreads();

    for (int e = tid; e < NE; e += 256)
        if (lhist[e]) lbase[e] = atomicAdd((int*)ws + WS_CURSOR + e, lhist[e]);
    __syncthreads();

    const int pos = lbase[j] + atomicAdd(&lcur[j], 1);
    ((int*)ws)[WS_SORTED + pos] = r;
}

// ============================================================
// sum: ROUND-13 VERBATIM. Fused segment-sum + Q write + IND + diff.
// 32 slots/wave, 1024 blocks, 8-row batched loads, per-block LDS
// diff reduction.
// ============================================================
__global__ __launch_bounds__(256) void sum_kernel(const float* __restrict__ input,
                                                  float* __restrict__ ws,
                                                  float* __restrict__ out) {
    __shared__ float wred[4];
    const int lane = threadIdx.x & 63;
    const int wv   = threadIdx.x >> 6;
    const int i0   = (blockIdx.x * 4 + wv) * 32;

    const int rv = ((const int*)ws)[WS_SORTED + i0 + (lane & 31)];
    const int jv = ((const int*)ws)[WS_IDX + rv];

    float acc  = 0.0f;
    float dacc = 0.0f;
    int   jcur = __shfl(jv, 0, 64);

    #pragma unroll
    for (int k = 0; k < 32; k += 8) {
        int   rr[8], jj[8];
        float v[8], q[8];
        #pragma unroll
        for (int u = 0; u < 8; u++) {
            rr[u] = __shfl(rv, k + u, 64);
            jj[u] = __shfl(jv, k + u, 64);
        }
        #pragma unroll
        for (int u = 0; u < 8; u++) v[u] = input[(size_t)rr[u] * DIM + lane];
        #pragma unroll
        for (int u = 0; u < 8; u++) q[u] = ws[WS_ET + jj[u] * DIM + lane];

        #pragma unroll
        for (int u = 0; u < 8; u++) {
            out[Q_OFF + (size_t)rr[u] * DIM + lane] = q[u];
            float dd = q[u] - v[u];
            dacc = fmaf(dd, dd, dacc);
            if (lane == 0) out[IND_OFF + rr[u]] = (float)jj[u];
            if (jj[u] != jcur) {
                atomicAdd(&ws[WS_ACCUM + jcur * DIM + lane], acc);
                acc = 0.0f;
                jcur = jj[u];
            }
            acc += v[u];
        }
    }
    atomicAdd(&ws[WS_ACCUM + jcur * DIM + lane], acc);

    #pragma unroll
    for (int off = 1; off < 64; off <<= 1) dacc += __shfl_xor(dacc, off, 64);
    if (lane == 0) wred[wv] = dacc;
    __syncthreads();
    if (threadIdx.x == 0)
        atomicAdd(&ws[WS_DIFF], wred[0] + wred[1] + wred[2] + wred[3]);
}

// ============================================================
// emaout: fused new_embed_avg + new_embed epilogue + diff finalize.
// ============================================================
__global__ __launch_bounds__(512) void emaout_kernel(const float* __restrict__ embed_avg,
                                                     const float* __restrict__ ws,
                                                     float* __restrict__ out) {
    const int e = blockIdx.x * 512 + threadIdx.x;
    const int d = e >> 9;
    const int j = e & (NE - 1);
    float s   = ws[WS_ACCUM + j * DIM + d];
    float avg = fmaf(embed_avg[e], DECAYF, OMDECAY * s);
    out[AVG_OFF + e] = avg;
    out[EMB_OFF + e] = avg / ws[WS_CSDIV + j];
    if (e == 0) out[DIFF_OFF] = ws[WS_DIFF] * (1.0f / 8388608.0f);
}

// ============================================================
extern "C" void kernel_launch(void* const* d_in, const int* in_sizes, int n_in,
                              void* d_out, int out_size, void* d_ws, size_t ws_size,
                              hipStream_t stream) {
    const float* input        = (const float*)d_in[0];
    const float* embed        = (const float*)d_in[1];
    const float* cluster_size = (const float*)d_in[2];
    const float* embed_avg    = (const float*)d_in[3];
    float* out = (float*)d_out;
    float* ws  = (float*)d_ws;

    prep_kernel<<<512, 64, 0, stream>>>(embed, ws);
    dist_kernel<<<N_ROWS / 128, 256, 0, stream>>>(input, ws);
    refine_kernel<<<512, 256, 0, stream>>>(input, ws);
    hist_kernel<<<128, 256, 0, stream>>>(ws);
    scanfin_kernel<<<1, 512, 0, stream>>>(cluster_size, ws, out);
    place_kernel<<<512, 256, 0, stream>>>(ws);
    sum_kernel<<<N_ROWS / 128, 256, 0, stream>>>(input, ws, out);
    emaout_kernel<<<64, 512, 0, stream>>>(embed_avg, ws, out);
}

// Round 19
// 115.724 us; speedup vs baseline: 1.1997x; 1.0027x over previous
//
#include <hip/hip_runtime.h>

typedef __attribute__((ext_vector_type(8))) short short8_t;
typedef __attribute__((ext_vector_type(4))) float f32x4;

// ---------------- problem constants ----------------
#define N_ROWS   131072     // 32*64*64
#define DIM      64
#define NE       512
#define DECAYF   0.99f
#define OMDECAY  0.01f
#define EPSF     1e-5f
#define GAP_THR  0.02f      // round-5/11/13 proven threshold

// ---------------- d_out offsets (floats) ----------------
#define Q_OFF    0            // 8388608
#define DIFF_OFF 8388608      // 1
#define IND_OFF  8388609      // 131072
#define CS_OFF   8519681      // 512
#define AVG_OFF  8520193      // 32768
#define EMB_OFF  8552961      // 32768

// ---------------- ws offsets (floats) ----------------
#define WS_ET      0            // 32768 : ET fp32 [code][dim]
#define WS_ENORM   32768        // 512   : ||E_j||^2 fp32
#define WS_EN64    33280        // 1024  : ||E_j||^2 fp64 (512 doubles)
#define WS_CSDIV   34304        // 512   : cs divisor
#define WS_DIFF    34816        // 1
#define WS_RCNT    34817        // 1 (int)
#define WS_IDX     34818        // 131072 (int)
#define WS_RLIST   165890       // 131072 (int)
#define WS_BH      296964       // 16384 floats = 32768 ushort: bf16 hi B-fragments
#define WS_BL      313348       // 16384 floats = 32768 ushort: bf16 lo B-fragments
#define WS_HIST    329732       // 512 (int)
#define WS_BINBASE 330244       // 512 (int)
#define WS_CURSOR  330756       // 512 (int)
#define WS_SORTED  331268       // 131072 (int)
#define WS_ACCUM   462340       // 32768 : embed_sum accumulator [code][dim]

__device__ __forceinline__ ushort f32_to_bf16_rn(float f) {
    unsigned u = __float_as_uint(f);
    unsigned r = (u + 0x7FFFu + ((u >> 16) & 1u)) >> 16;
    return (ushort)r;
}
__device__ __forceinline__ float bf16_to_f32(ushort h) {
    return __uint_as_float(((unsigned)h) << 16);
}

// ============================================================
// prep: merged prep1+prep2. Block per code (512 x 64).
// ============================================================
__global__ __launch_bounds__(64) void prep_kernel(const float* __restrict__ embed,
                                                  float* __restrict__ ws) {
    const int c = blockIdx.x;    // code 0..511
    const int d = threadIdx.x;   // dim 0..63
    float v = embed[d * NE + c];
    ws[WS_ET + c * DIM + d] = v;

    ushort hb = f32_to_bf16_rn(v);
    float  lf = v - bf16_to_f32(hb);
    ushort lb = f32_to_bf16_rn(lf);

    // fragment order: tile T=c>>4, n=c&15, kstep s=d>>5, k8=(d>>3)&3, j=d&7
    const int T  = c >> 4;
    const int n  = c & 15;
    const int s  = d >> 5;
    const int k8 = (d >> 3) & 3;
    const int jj = d & 7;
    const int l  = k8 * 16 + n;
    const int idx = (T * 2 + s) * 512 + l * 8 + jj;
    ((ushort*)(ws + WS_BH))[idx] = hb;
    ((ushort*)(ws + WS_BL))[idx] = lb;

    double sq = (double)v * (double)v;
    #pragma unroll
    for (int off = 32; off > 0; off >>= 1) sq += __shfl_down(sq, off, 64);
    if (d == 0) {
        ws[WS_ENORM + c] = (float)sq;
        ((double*)(ws + WS_EN64))[c] = sq;
        ((int*)ws)[WS_HIST + c] = 0;
        if (c == 0) {
            ws[WS_DIFF] = 0.0f;
            ((int*)ws)[WS_RCNT] = 0;
        }
    }
    ws[WS_ACCUM + c * DIM + d] = 0.0f;
}

// ============================================================
// dist: ROUND-13 VERBATIM (measured 44.1 us). Barrier-free, NO LDS.
// 9 structural-modification attempts all regressed — do not touch.
// 1024 blocks x 256 threads (4 waves); wave = 32 rows x 512 codes.
// ============================================================
__global__ __launch_bounds__(256) void dist_kernel(const float* __restrict__ input,
                                                   float* __restrict__ ws) {
    const int tid  = threadIdx.x;
    const int lane = tid & 63;
    const int wv   = tid >> 6;
    const int r0   = blockIdx.x * 128 + wv * 32;
    const int n15  = lane & 15;
    const int koff = (lane >> 4) * 8;

    short8_t Ahi[2][2], Alo[2][2];
    #pragma unroll
    for (int sub = 0; sub < 2; sub++) {
        const float* rp = input + (size_t)(r0 + sub * 16 + n15) * DIM + koff;
        #pragma unroll
        for (int s = 0; s < 2; s++) {
            float4 x0 = *(const float4*)(rp + s * 32);
            float4 x1 = *(const float4*)(rp + s * 32 + 4);
            float xf[8] = {x0.x, x0.y, x0.z, x0.w, x1.x, x1.y, x1.z, x1.w};
            short8_t h, l;
            #pragma unroll
            for (int e = 0; e < 8; e++) {
                ushort hb = f32_to_bf16_rn(xf[e]);
                float  lf = xf[e] - bf16_to_f32(hb);
                ushort lb = f32_to_bf16_rn(lf);
                h[e] = (short)hb;
                l[e] = (short)lb;
            }
            Ahi[sub][s] = h;
            Alo[sub][s] = l;
        }
    }

    const ushort* bhp = (const ushort*)(ws + WS_BH) + lane * 8;
    const ushort* blp = (const ushort*)(ws + WS_BL) + lane * 8;

    float m1[8], m2[8];
    int   j1[8];
    #pragma unroll
    for (int i = 0; i < 8; i++) { m1[i] = 3.4e38f; m2[i] = 3.4e38f; j1[i] = 0; }

    #pragma unroll 2
    for (int T = 0; T < 32; T++) {
        short8_t Bh0 = *(const short8_t*)(bhp + T * 1024);
        short8_t Bh1 = *(const short8_t*)(bhp + T * 1024 + 512);
        short8_t Bl0 = *(const short8_t*)(blp + T * 1024);
        short8_t Bl1 = *(const short8_t*)(blp + T * 1024 + 512);

        f32x4 aa = {0.f, 0.f, 0.f, 0.f};
        f32x4 ab = {0.f, 0.f, 0.f, 0.f};
        aa = __builtin_amdgcn_mfma_f32_16x16x32_bf16(Ahi[0][0], Bh0, aa, 0, 0, 0);
        ab = __builtin_amdgcn_mfma_f32_16x16x32_bf16(Ahi[1][0], Bh0, ab, 0, 0, 0);
        aa = __builtin_amdgcn_mfma_f32_16x16x32_bf16(Alo[0][0], Bh0, aa, 0, 0, 0);
        ab = __builtin_amdgcn_mfma_f32_16x16x32_bf16(Alo[1][0], Bh0, ab, 0, 0, 0);
        aa = __builtin_amdgcn_mfma_f32_16x16x32_bf16(Ahi[0][0], Bl0, aa, 0, 0, 0);
        ab = __builtin_amdgcn_mfma_f32_16x16x32_bf16(Ahi[1][0], Bl0, ab, 0, 0, 0);
        aa = __builtin_amdgcn_mfma_f32_16x16x32_bf16(Ahi[0][1], Bh1, aa, 0, 0, 0);
        ab = __builtin_amdgcn_mfma_f32_16x16x32_bf16(Ahi[1][1], Bh1, ab, 0, 0, 0);
        aa = __builtin_amdgcn_mfma_f32_16x16x32_bf16(Alo[0][1], Bh1, aa, 0, 0, 0);
        ab = __builtin_amdgcn_mfma_f32_16x16x32_bf16(Alo[1][1], Bh1, ab, 0, 0, 0);
        aa = __builtin_amdgcn_mfma_f32_16x16x32_bf16(Ahi[0][1], Bl1, aa, 0, 0, 0);
        ab = __builtin_amdgcn_mfma_f32_16x16x32_bf16(Ahi[1][1], Bl1, ab, 0, 0, 0);

        const float en = ws[WS_ENORM + T * 16 + n15];
        const int   jc = T * 16 + n15;
        #pragma unroll
        for (int q = 0; q < 4; q++) {
            float da = fmaf(-2.0f, aa[q], en);
            m2[q]    = fminf(m2[q], fmaxf(m1[q], da));
            j1[q]    = (da < m1[q]) ? jc : j1[q];
            m1[q]    = fminf(m1[q], da);
            float db = fmaf(-2.0f, ab[q], en);
            m2[q+4]  = fminf(m2[q+4], fmaxf(m1[q+4], db));
            j1[q+4]  = (db < m1[q+4]) ? jc : j1[q+4];
            m1[q+4]  = fminf(m1[q+4], db);
        }
    }

    #pragma unroll
    for (int off = 1; off < 16; off <<= 1) {
        #pragma unroll
        for (int i = 0; i < 8; i++) {
            float b1 = __shfl_xor(m1[i], off, 64);
            float b2 = __shfl_xor(m2[i], off, 64);
            int   bj = __shfl_xor(j1[i], off, 64);
            float a1 = m1[i];
            float nm2 = fminf(fminf(m2[i], b2), fmaxf(a1, b1));
            bool takeB = (b1 < a1) || (b1 == a1 && bj < j1[i]);
            m1[i] = takeB ? b1 : a1;
            j1[i] = takeB ? bj : j1[i];
            m2[i] = nm2;
        }
    }

    if (n15 == 0) {
        #pragma unroll
        for (int i = 0; i < 8; i++) {
            int sub = i >> 2, q = i & 3;
            int r = r0 + sub * 16 + (lane >> 4) * 4 + q;
            ((int*)ws)[WS_IDX + r] = j1[i];
            if (m2[i] - m1[i] < GAP_THR) {
                int pos = atomicAdd((int*)ws + WS_RCNT, 1);
                ((int*)ws)[WS_RLIST + pos] = r;
            }
        }
    }
}

// ============================================================
// refine: exact fp64 re-resolution of flagged rows (fix IDX only).
// ============================================================
__global__ __launch_bounds__(256) void refine_kernel(const float* __restrict__ input,
                                                     float* __restrict__ ws) {
    __shared__ float rowf[4][DIM];
    const int cnt  = ((const int*)ws)[WS_RCNT];
    const int lane = threadIdx.x & 63;
    const int wv   = threadIdx.x >> 6;
    const double* en64 = (const double*)(ws + WS_EN64);

    for (int ii = blockIdx.x * 4 + wv; ii < cnt; ii += 2048) {
        const int r = ((const int*)ws)[WS_RLIST + ii];
        rowf[wv][lane] = input[(size_t)r * DIM + lane];
        double bd = 1e300;
        int    bj = 0x7fffffff;
        for (int kk = 0; kk < 8; kk++) {
            int j = kk * 64 + lane;
            const float* ep = ws + WS_ET + j * DIM;
            double s0 = 0.0, s1 = 0.0;
            #pragma unroll 8
            for (int d = 0; d < DIM; d += 2) {
                s0 = fma((double)ep[d],     (double)rowf[wv][d],     s0);
                s1 = fma((double)ep[d + 1], (double)rowf[wv][d + 1], s1);
            }
            double dist = en64[j] - 2.0 * (s0 + s1);
            if (dist < bd || (dist == bd && j < bj)) { bd = dist; bj = j; }
        }
        #pragma unroll
        for (int off = 32; off > 0; off >>= 1) {
            double od = __shfl_down(bd, off, 64);
            int    oj = __shfl_down(bj, off, 64);
            if (od < bd || (od == bd && oj < bj)) { bd = od; bj = oj; }
        }
        if (lane == 0) ((int*)ws)[WS_IDX + r] = bj;
    }
}

// ============================================================
// hist: build WS_HIST from final IDX. 128 blocks x 256 threads.
// ============================================================
__global__ __launch_bounds__(256) void hist_kernel(float* __restrict__ ws) {
    __shared__ int hist[NE];
    const int tid = threadIdx.x;
    for (int e = tid; e < NE; e += 256) hist[e] = 0;
    __syncthreads();

    const int4 j4 = *((const int4*)((const int*)ws + WS_IDX) + blockIdx.x * 256 + tid);
    atomicAdd(&hist[j4.x], 1);
    atomicAdd(&hist[j4.y], 1);
    atomicAdd(&hist[j4.z], 1);
    atomicAdd(&hist[j4.w], 1);
    __syncthreads();

    for (int e = tid; e < NE; e += 256) {
        int h = hist[e];
        if (h) atomicAdd((int*)ws + WS_HIST + e, h);
    }
}

// ============================================================
// scanfin (1 block x 512): CS EMA, exclusive scan -> binbase/cursor,
// n-reduce, cs divisor.
// ============================================================
__global__ __launch_bounds__(512) void scanfin_kernel(const float* __restrict__ cluster_size,
                                                      float* __restrict__ ws,
                                                      float* __restrict__ out) {
    __shared__ int wsums[8];
    __shared__ float red[8];
    const int t    = threadIdx.x;
    const int lane = t & 63;
    const int wv   = t >> 6;
    const int v    = ((const int*)ws)[WS_HIST + t];
    const float csnew = fmaf(cluster_size[t], DECAYF, OMDECAY * (float)v);
    out[CS_OFF + t] = csnew;

    int x = v;
    #pragma unroll
    for (int off = 1; off < 64; off <<= 1) {
        int y = __shfl_up(x, off, 64);
        if (lane >= off) x += y;
    }
    if (lane == 63) wsums[wv] = x;

    float s = csnew;
    #pragma unroll
    for (int off = 32; off > 0; off >>= 1) s += __shfl_down(s, off, 64);
    if (lane == 0) red[wv] = s;
    __syncthreads();

    int add = 0;
    for (int w = 0; w < wv; w++) add += wsums[w];
    const int excl = x + add - v;
    ((int*)ws)[WS_BINBASE + t] = excl;
    ((int*)ws)[WS_CURSOR + t]  = excl;

    float n = red[0] + red[1] + red[2] + red[3] + red[4] + red[5] + red[6] + red[7];
    ws[WS_CSDIV + t] = (csnew + EPSF) / (n + (float)NE * EPSF) * n;
}

// ============================================================
// place: skew-proof counting-sort placement.
// ============================================================
__global__ __launch_bounds__(256) void place_kernel(float* __restrict__ ws) {
    __shared__ int lhist[NE];
    __shared__ int lbase[NE];
    __shared__ int lcur[NE];
    const int tid  = threadIdx.x;
    const int base = blockIdx.x * 256;

    for (int e = tid; e < NE; e += 256) { lhist[e] = 0; lcur[e] = 0; }
    __syncthreads();

    const int r = base + tid;
    const int j = ((const int*)ws)[WS_IDX + r];
    atomicAdd(&lhist[j], 1);
    __syncthreads();

    for (int e = tid; e < NE; e += 256)
        if (lhist[e]) lbase[e] = atomicAdd((int*)ws + WS_CURSOR + e, lhist[e]);
    __syncthreads();

    const int pos = lbase[j] + atomicAdd(&lcur[j], 1);
    ((int*)ws)[WS_SORTED + pos] = r;
}

// ============================================================
// sum: fused segment-sum + Q write + IND + diff. Round-13 semantics,
// ILP deepened 8 -> 16 rows per batch (2 batches cover the wave's 32
// slots): doubles gathers in flight; 1024 blocks / 32 slots unchanged
// (round 12 proved more waves = atomic serialization; this raises ILP
// without changing wave count or atomic frequency).
// ============================================================
__global__ __launch_bounds__(256) void sum_kernel(const float* __restrict__ input,
                                                  float* __restrict__ ws,
                                                  float* __restrict__ out) {
    __shared__ float wred[4];
    const int lane = threadIdx.x & 63;
    const int wv   = threadIdx.x >> 6;
    const int i0   = (blockIdx.x * 4 + wv) * 32;

    const int rv = ((const int*)ws)[WS_SORTED + i0 + (lane & 31)];
    const int jv = ((const int*)ws)[WS_IDX + rv];

    float acc  = 0.0f;
    float dacc = 0.0f;
    int   jcur = __shfl(jv, 0, 64);

    #pragma unroll
    for (int k = 0; k < 32; k += 16) {
        int   rr[16], jj[16];
        float v[16], q[16];
        #pragma unroll
        for (int u = 0; u < 16; u++) {
            rr[u] = __shfl(rv, k + u, 64);
            jj[u] = __shfl(jv, k + u, 64);
        }
        #pragma unroll
        for (int u = 0; u < 16; u++) v[u] = input[(size_t)rr[u] * DIM + lane];
        #pragma unroll
        for (int u = 0; u < 16; u++) q[u] = ws[WS_ET + jj[u] * DIM + lane];

        #pragma unroll
        for (int u = 0; u < 16; u++) {
            out[Q_OFF + (size_t)rr[u] * DIM + lane] = q[u];
            float dd = q[u] - v[u];
            dacc = fmaf(dd, dd, dacc);
            if (lane == 0) out[IND_OFF + rr[u]] = (float)jj[u];
            if (jj[u] != jcur) {
                atomicAdd(&ws[WS_ACCUM + jcur * DIM + lane], acc);
                acc = 0.0f;
                jcur = jj[u];
            }
            acc += v[u];
        }
    }
    atomicAdd(&ws[WS_ACCUM + jcur * DIM + lane], acc);

    #pragma unroll
    for (int off = 1; off < 64; off <<= 1) dacc += __shfl_xor(dacc, off, 64);
    if (lane == 0) wred[wv] = dacc;
    __syncthreads();
    if (threadIdx.x == 0)
        atomicAdd(&ws[WS_DIFF], wred[0] + wred[1] + wred[2] + wred[3]);
}

// ============================================================
// emaout: fused new_embed_avg + new_embed epilogue + diff finalize.
// ============================================================
__global__ __launch_bounds__(512) void emaout_kernel(const float* __restrict__ embed_avg,
                                                     const float* __restrict__ ws,
                                                     float* __restrict__ out) {
    const int e = blockIdx.x * 512 + threadIdx.x;
    const int d = e >> 9;
    const int j = e & (NE - 1);
    float s   = ws[WS_ACCUM + j * DIM + d];
    float avg = fmaf(embed_avg[e], DECAYF, OMDECAY * s);
    out[AVG_OFF + e] = avg;
    out[EMB_OFF + e] = avg / ws[WS_CSDIV + j];
    if (e == 0) out[DIFF_OFF] = ws[WS_DIFF] * (1.0f / 8388608.0f);
}

// ============================================================
extern "C" void kernel_launch(void* const* d_in, const int* in_sizes, int n_in,
                              void* d_out, int out_size, void* d_ws, size_t ws_size,
                              hipStream_t stream) {
    const float* input        = (const float*)d_in[0];
    const float* embed        = (const float*)d_in[1];
    const float* cluster_size = (const float*)d_in[2];
    const float* embed_avg    = (const float*)d_in[3];
    float* out = (float*)d_out;
    float* ws  = (float*)d_ws;

    prep_kernel<<<512, 64, 0, stream>>>(embed, ws);
    dist_kernel<<<N_ROWS / 128, 256, 0, stream>>>(input, ws);
    refine_kernel<<<512, 256, 0, stream>>>(input, ws);
    hist_kernel<<<128, 256, 0, stream>>>(ws);
    scanfin_kernel<<<1, 512, 0, stream>>>(cluster_size, ws, out);
    place_kernel<<<512, 256, 0, stream>>>(ws);
    sum_kernel<<<N_ROWS / 128, 256, 0, stream>>>(input, ws, out);
    emaout_kernel<<<64, 512, 0, stream>>>(embed_avg, ws, out);
}